// Round 2
// baseline (1070.658 us; speedup 1.0000x reference)
//
#include <hip/hip_runtime.h>
#include <stdint.h>

// CrossStreamAttention: B=32768, D=512, H=8, S=3, DH=64
// Chunked pipeline (R2): per batch-chunk Bc: pack bf16 -> GEMM(qkv) -> attn ->
// GEMM(proj+res) -> gate softmax*x -> GEMM(mlp1+silu) -> GEMM(mlp2->f32) -> LN.
// Scratch peak = 6.3MB weights + 15360*Bc bytes; Bc adaptively halved to fit ws_size.

typedef float f32x4 __attribute__((ext_vector_type(4)));
typedef short bf16x8 __attribute__((ext_vector_type(8)));  // 8 bf16 in 4 VGPRs

__device__ __forceinline__ float bf2f(unsigned short h) {
  return __uint_as_float(((unsigned)h) << 16);
}
__device__ __forceinline__ unsigned short f2bf(float f) {
  unsigned u = __float_as_uint(f);
  u += 0x7FFFu + ((u >> 16) & 1u);   // RNE
  return (unsigned short)(u >> 16);
}
__device__ __forceinline__ ushort4 f2bf4(float4 v) {
  return make_ushort4(f2bf(v.x), f2bf(v.y), f2bf(v.z), f2bf(v.w));
}

__device__ __forceinline__ void async_cp16(const void* g, void* lds) {
  __builtin_amdgcn_global_load_lds(
      (const __attribute__((address_space(1))) void*)g,
      (__attribute__((address_space(3))) void*)lds, 16, 0, 0);
}

// ---------------------------------------------------------------- converts
__global__ void __launch_bounds__(256) cvtbf(const float4* __restrict__ src,
                                             ushort4* __restrict__ dst, int n4) {
  int i = blockIdx.x * 256 + threadIdx.x;
  if (i < n4) dst[i] = f2bf4(src[i]);
}

// pack stacked[b,s,:] = input_s[b,:], bf16.  tid over Bc*128 float4s.
__global__ void __launch_bounds__(256) pack3(const float4* __restrict__ X0,
                                             const float4* __restrict__ X1,
                                             const float4* __restrict__ X2,
                                             ushort4* __restrict__ S) {
  int tid = blockIdx.x * 256 + threadIdx.x;   // b*128 + c
  int b = tid >> 7, c = tid & 127;
  long base = (long)(3 * b) * 128 + c;
  S[base]       = f2bf4(X0[tid]);
  S[base + 128] = f2bf4(X1[tid]);
  S[base + 256] = f2bf4(X2[tid]);
}

// ---------------------------------------------------------------- GEMM
// C[M,N] = A[M,K] @ W[N,K]^T + bias, epilogues below. 128x128 tile, BK=64,
// 4 waves (2x2), each wave 64x64 via 4x4 grid of 16x16x32 bf16 MFMA.
// LDS staged via global_load_lds width=16 with XOR-swizzled 16B chunks.
enum { EPI_BF16 = 0, EPI_RES = 1, EPI_SILU = 2, EPI_F32 = 3 };

template <int EPI>
__global__ void __launch_bounds__(256)
gemm_bt(const unsigned short* __restrict__ A,
        const unsigned short* __restrict__ W,
        const float* __restrict__ bias,
        const unsigned short* __restrict__ Res,
        void* __restrict__ Out,
        int K, int N) {
  __shared__ unsigned short As[128 * 64];
  __shared__ unsigned short Bs[128 * 64];
  const int t = threadIdx.x;
  const int lane = t & 63;
  const int wave = t >> 6;
  const int wm = wave >> 1, wn = wave & 1;
  const long bm = (long)blockIdx.y * 128;
  const long bn = (long)blockIdx.x * 128;

  // staging: thread t -> LDS bytes [t*16, t*16+16) (+ issue*4KB), i.e. tile
  // row = t>>3 (+32*i), slot-chunk = t&7. Source k-chunk XOR-swizzled by row.
  const int srow = t >> 3;
  const int schunk = ((t & 7) ^ (srow & 7)) << 3;  // element offset
  const unsigned short* Ag = A + (bm + srow) * (long)K + schunk;
  const unsigned short* Wg = W + (bn + srow) * (long)K + schunk;
  unsigned short* AsD = As + t * 8;
  unsigned short* BsD = Bs + t * 8;

  f32x4 acc[4][4] = {};
  const int arow0 = wm * 64 + (lane & 15);
  const int brow0 = wn * 64 + (lane & 15);

  for (int k0 = 0; k0 < K; k0 += 64) {
    __syncthreads();
#pragma unroll
    for (int i = 0; i < 4; i++) {
      async_cp16(Ag + (long)(i * 32) * K + k0, AsD + i * 2048);
      async_cp16(Wg + (long)(i * 32) * K + k0, BsD + i * 2048);
    }
    __syncthreads();
#pragma unroll
    for (int kk = 0; kk < 2; kk++) {
      // global k-chunk q = kk*4 + (lane>>4); stored at slot q ^ (row&7); row&7 == lane&7
      const int sc = ((kk * 4 + (lane >> 4)) ^ (lane & 7)) << 3;
      bf16x8 af[4], bfr[4];
#pragma unroll
      for (int mt = 0; mt < 4; mt++)
        af[mt] = *(const bf16x8*)&As[(arow0 + mt * 16) * 64 + sc];
#pragma unroll
      for (int nt = 0; nt < 4; nt++)
        bfr[nt] = *(const bf16x8*)&Bs[(brow0 + nt * 16) * 64 + sc];
#pragma unroll
      for (int mt = 0; mt < 4; mt++)
#pragma unroll
        for (int nt = 0; nt < 4; nt++)
          acc[mt][nt] = __builtin_amdgcn_mfma_f32_16x16x32_bf16(
              af[mt], bfr[nt], acc[mt][nt], 0, 0, 0);
    }
  }

  // C/D layout: col = lane&15, row = (lane>>4)*4 + r
  const long row0 = bm + wm * 64 + ((lane >> 4) << 2);
  const int col0 = (int)bn + wn * 64 + (lane & 15);
#pragma unroll
  for (int nt = 0; nt < 4; nt++) {
    const int col = col0 + nt * 16;
    const float bv = bias[col];
#pragma unroll
    for (int mt = 0; mt < 4; mt++) {
      const long rbase = row0 + mt * 16;
#pragma unroll
      for (int r = 0; r < 4; r++) {
        float v = acc[mt][nt][r] + bv;
        const long idx = (rbase + r) * (long)N + col;
        if (EPI == EPI_RES) v += bf2f(Res[idx]);
        if (EPI == EPI_SILU) v = v * (1.0f / (1.0f + __expf(-v)));
        if (EPI == EPI_F32)
          ((float*)Out)[idx] = v;
        else
          ((unsigned short*)Out)[idx] = f2bf(v);
      }
    }
  }
}

// ---------------------------------------------------------------- attention
// one wave per (b,h); lane = d in [0,64). qkv row m=3b+s: [q(512)|k(512)|v(512)]
__global__ void __launch_bounds__(256) attn3(const unsigned short* __restrict__ QKV,
                                             unsigned short* __restrict__ AO) {
  int idx = blockIdx.x * 4 + (threadIdx.x >> 6);
  int lane = threadIdx.x & 63;
  int b = idx >> 3, h = idx & 7;
  const unsigned short* base = QKV + (long)(3 * b) * 1536 + h * 64 + lane;
  float q[3], k[3], v[3];
#pragma unroll
  for (int s = 0; s < 3; s++) {
    const unsigned short* r = base + s * 1536;
    q[s] = bf2f(r[0]);
    k[s] = bf2f(r[512]);
    v[s] = bf2f(r[1024]);
  }
  float sc[3][3];
#pragma unroll
  for (int s = 0; s < 3; s++)
#pragma unroll
    for (int u = 0; u < 3; u++) sc[s][u] = q[s] * k[u];
#pragma unroll
  for (int m = 1; m < 64; m <<= 1)
#pragma unroll
    for (int s = 0; s < 3; s++)
#pragma unroll
      for (int u = 0; u < 3; u++) sc[s][u] += __shfl_xor(sc[s][u], m, 64);

  unsigned short* ob = AO + (long)(3 * b) * 512 + h * 64 + lane;
#pragma unroll
  for (int s = 0; s < 3; s++) {
    float a0 = sc[s][0] * 0.125f, a1 = sc[s][1] * 0.125f, a2 = sc[s][2] * 0.125f;
    float mx = fmaxf(a0, fmaxf(a1, a2));
    float e0 = __expf(a0 - mx), e1 = __expf(a1 - mx), e2 = __expf(a2 - mx);
    float inv = 1.0f / (e0 + e1 + e2);
    ob[s * 512] = f2bf((e0 * v[0] + e1 * v[1] + e2 * v[2]) * inv);
  }
}

// ---------------------------------------------------------------- gate
// one block per batch row: 3 dots over 1536, softmax, scale, write gated bf16
__global__ void __launch_bounds__(256) gate3(const unsigned short* __restrict__ AT,
                                             const float* __restrict__ WG,
                                             const float* __restrict__ BG,
                                             unsigned short* __restrict__ G) {
  int b = blockIdx.x, t = threadIdx.x;
  const unsigned short* row = AT + (long)b * 1536;
  float x[6], p0 = 0.f, p1 = 0.f, p2 = 0.f;
#pragma unroll
  for (int i = 0; i < 6; i++) {
    int e = i * 256 + t;
    float xv = bf2f(row[e]);
    x[i] = xv;
    p0 = fmaf(xv, WG[e], p0);
    p1 = fmaf(xv, WG[1536 + e], p1);
    p2 = fmaf(xv, WG[3072 + e], p2);
  }
#pragma unroll
  for (int m = 1; m < 64; m <<= 1) {
    p0 += __shfl_xor(p0, m, 64);
    p1 += __shfl_xor(p1, m, 64);
    p2 += __shfl_xor(p2, m, 64);
  }
  __shared__ float red[3][4];
  int lane = t & 63, wave = t >> 6;
  if (lane == 0) { red[0][wave] = p0; red[1][wave] = p1; red[2][wave] = p2; }
  __syncthreads();
  float g0 = red[0][0] + red[0][1] + red[0][2] + red[0][3] + BG[0];
  float g1 = red[1][0] + red[1][1] + red[1][2] + red[1][3] + BG[1];
  float g2 = red[2][0] + red[2][1] + red[2][2] + red[2][3] + BG[2];
  float mx = fmaxf(g0, fmaxf(g1, g2));
  g0 = __expf(g0 - mx); g1 = __expf(g1 - mx); g2 = __expf(g2 - mx);
  float inv = 1.0f / (g0 + g1 + g2);
  g0 *= inv; g1 *= inv; g2 *= inv;
  unsigned short* outp = G + (long)b * 1536;
#pragma unroll
  for (int i = 0; i < 6; i++) {
    float gs = (i < 2) ? g0 : ((i < 4) ? g1 : g2);  // stream = e>>9 = i>>1
    outp[i * 256 + t] = f2bf(x[i] * gs);
  }
}

// ---------------------------------------------------------------- layernorm
// one wave per row of 512 f32
__global__ void __launch_bounds__(256) lnorm(const float* __restrict__ F,
                                             const float* __restrict__ gamma,
                                             const float* __restrict__ beta,
                                             float* __restrict__ out) {
  int row = blockIdx.x * 4 + (threadIdx.x >> 6);
  int lane = threadIdx.x & 63;
  const float4* fr = (const float4*)(F + (long)row * 512);
  float4 a = fr[lane], c = fr[lane + 64];
  float s = a.x + a.y + a.z + a.w + c.x + c.y + c.z + c.w;
  float ss = a.x * a.x + a.y * a.y + a.z * a.z + a.w * a.w +
             c.x * c.x + c.y * c.y + c.z * c.z + c.w * c.w;
#pragma unroll
  for (int m = 1; m < 64; m <<= 1) {
    s += __shfl_xor(s, m, 64);
    ss += __shfl_xor(ss, m, 64);
  }
  float mean = s * (1.0f / 512.0f);
  float var = ss * (1.0f / 512.0f) - mean * mean;
  float rstd = rsqrtf(var + 1e-5f);
  const float4* g4 = (const float4*)gamma;
  const float4* b4 = (const float4*)beta;
  float4 g0 = g4[lane], g1 = g4[lane + 64], be0 = b4[lane], be1 = b4[lane + 64];
  float4 o0, o1;
  o0.x = (a.x - mean) * rstd * g0.x + be0.x;
  o0.y = (a.y - mean) * rstd * g0.y + be0.y;
  o0.z = (a.z - mean) * rstd * g0.z + be0.z;
  o0.w = (a.w - mean) * rstd * g0.w + be0.w;
  o1.x = (c.x - mean) * rstd * g1.x + be1.x;
  o1.y = (c.y - mean) * rstd * g1.y + be1.y;
  o1.z = (c.z - mean) * rstd * g1.z + be1.z;
  o1.w = (c.w - mean) * rstd * g1.w + be1.w;
  float4* orow = (float4*)(out + (long)row * 512);
  orow[lane] = o0;
  orow[lane + 64] = o1;
}

// ---------------------------------------------------------------- launch
extern "C" void kernel_launch(void* const* d_in, const int* in_sizes, int n_in,
                              void* d_out, int out_size, void* d_ws, size_t ws_size,
                              hipStream_t stream) {
  const float* kin    = (const float*)d_in[0];
  const float* colr   = (const float*)d_in[1];
  const float* spi    = (const float*)d_in[2];
  const float* w_in   = (const float*)d_in[3];
  const float* b_in   = (const float*)d_in[4];
  const float* w_out  = (const float*)d_in[5];
  const float* b_out  = (const float*)d_in[6];
  const float* w_gate = (const float*)d_in[7];
  const float* b_gate = (const float*)d_in[8];
  const float* w1     = (const float*)d_in[9];
  const float* b1     = (const float*)d_in[10];
  const float* w2     = (const float*)d_in[11];
  const float* b2     = (const float*)d_in[12];
  const float* gamma  = (const float*)d_in[13];
  const float* beta   = (const float*)d_in[14];
  float* out = (float*)d_out;

  // chunk size: peak scratch = 6,291,456 + 15360*Bc bytes; shrink to fit ws_size
  long Bc = 8192;
  while (Bc > 1024 && (size_t)(6291456 + 15360 * Bc) > ws_size) Bc >>= 1;
  const int nch = (int)(32768 / Bc);

  // weights (bf16), converted once
  char* ws = (char*)d_ws;
  unsigned short* Wic = (unsigned short*)(ws);              // w_in  1536x512
  unsigned short* Woc = (unsigned short*)(ws + 1572864);    // w_out 512x512
  unsigned short* W1c = (unsigned short*)(ws + 2097152);    // w1    1024x1536
  unsigned short* W2c = (unsigned short*)(ws + 5242880);    // w2    512x1024
  char* Sb   = ws + 6291456;                                // S_c   [3Bc,512] bf16
  char* QKVb = Sb + 3072 * Bc;                              // QKV_c [3Bc,1536] bf16
  char* AOb  = QKVb + 9216 * Bc;                            // AO_c  [3Bc,512] bf16

  cvtbf<<<768, 256, 0, stream>>>((const float4*)w_in, (ushort4*)Wic, 196608);
  cvtbf<<<256, 256, 0, stream>>>((const float4*)w_out, (ushort4*)Woc, 65536);
  cvtbf<<<1536, 256, 0, stream>>>((const float4*)w1, (ushort4*)W1c, 393216);
  cvtbf<<<512, 256, 0, stream>>>((const float4*)w2, (ushort4*)W2c, 131072);

  for (int c = 0; c < nch; c++) {
    const long boff = (long)c * Bc;
    unsigned short* S_c   = (unsigned short*)Sb;
    unsigned short* QKV_c = (unsigned short*)QKVb;
    unsigned short* AO_c  = (unsigned short*)AOb;
    unsigned short* AT_c  = QKV_c;                          // [3Bc,512], aliases QKV (dead)
    unsigned short* G_c   = (unsigned short*)(QKVb + 3072 * Bc);  // [Bc,1536], after AT
    unsigned short* H_c   = AO_c;                           // [Bc,1024], aliases AO (dead)
    float*          F_c   = (float*)QKVb;                   // [Bc,512] f32, aliases AT (dead)

    pack3<<<(int)(Bc / 2), 256, 0, stream>>>(
        (const float4*)(kin + boff * 512), (const float4*)(colr + boff * 512),
        (const float4*)(spi + boff * 512), (ushort4*)S_c);
    // qkv = S @ w_in^T + b_in           M=3Bc N=1536 K=512
    gemm_bt<EPI_BF16><<<dim3(12, (int)(3 * Bc / 128)), 256, 0, stream>>>(
        S_c, Wic, b_in, nullptr, QKV_c, 512, 1536);
    attn3<<<(int)(Bc * 2), 256, 0, stream>>>(QKV_c, AO_c);
    // attn_out = S + AO @ w_out^T + b_out   M=3Bc N=512 K=512
    gemm_bt<EPI_RES><<<dim3(4, (int)(3 * Bc / 128)), 256, 0, stream>>>(
        AO_c, Woc, b_out, S_c, AT_c, 512, 512);
    gate3<<<(int)Bc, 256, 0, stream>>>(AT_c, w_gate, b_gate, G_c);
    // h = silu(G @ w1^T + b1)           M=Bc N=1024 K=1536
    gemm_bt<EPI_SILU><<<dim3(8, (int)(Bc / 128)), 256, 0, stream>>>(
        G_c, W1c, b1, nullptr, H_c, 1536, 1024);
    // fused = h @ w2^T + b2 (f32)       M=Bc N=512 K=1024
    gemm_bt<EPI_F32><<<dim3(4, (int)(Bc / 128)), 256, 0, stream>>>(
        H_c, W2c, b2, nullptr, F_c, 1024, 512);
    lnorm<<<(int)(Bc / 4), 256, 0, stream>>>(F_c, gamma, beta, out + boff * 512);
  }
}

// Round 3
// 865.826 us; speedup vs baseline: 1.2366x; 1.2366x over previous
//
#include <hip/hip_runtime.h>
#include <stdint.h>

// CrossStreamAttention: B=32768, D=512, H=8, S=3, DH=64
// R3: chunked pipeline (adaptive Bc, starts at 32768) + XCD-grouped tile
// swizzle in gemm_bt (A-panel L2 locality) + 4x-vectorized attention.

typedef float f32x4 __attribute__((ext_vector_type(4)));
typedef short bf16x8 __attribute__((ext_vector_type(8)));  // 8 bf16 in 4 VGPRs

__device__ __forceinline__ float bf2f(unsigned short h) {
  return __uint_as_float(((unsigned)h) << 16);
}
__device__ __forceinline__ unsigned short f2bf(float f) {
  unsigned u = __float_as_uint(f);
  u += 0x7FFFu + ((u >> 16) & 1u);   // RNE
  return (unsigned short)(u >> 16);
}
__device__ __forceinline__ ushort4 f2bf4(float4 v) {
  return make_ushort4(f2bf(v.x), f2bf(v.y), f2bf(v.z), f2bf(v.w));
}

__device__ __forceinline__ void async_cp16(const void* g, void* lds) {
  __builtin_amdgcn_global_load_lds(
      (const __attribute__((address_space(1))) void*)g,
      (__attribute__((address_space(3))) void*)lds, 16, 0, 0);
}

// ---------------------------------------------------------------- converts
__global__ void __launch_bounds__(256) cvtbf(const float4* __restrict__ src,
                                             ushort4* __restrict__ dst, int n4) {
  int i = blockIdx.x * 256 + threadIdx.x;
  if (i < n4) dst[i] = f2bf4(src[i]);
}

// pack stacked[b,s,:] = input_s[b,:], bf16.  tid over Bc*128 float4s.
__global__ void __launch_bounds__(256) pack3(const float4* __restrict__ X0,
                                             const float4* __restrict__ X1,
                                             const float4* __restrict__ X2,
                                             ushort4* __restrict__ S) {
  int tid = blockIdx.x * 256 + threadIdx.x;   // b*128 + c
  int b = tid >> 7, c = tid & 127;
  long base = (long)(3 * b) * 128 + c;
  S[base]       = f2bf4(X0[tid]);
  S[base + 128] = f2bf4(X1[tid]);
  S[base + 256] = f2bf4(X2[tid]);
}

// ---------------------------------------------------------------- GEMM
// C[M,N] = A[M,K] @ W[N,K]^T + bias. 128x128 tile, BK=64, 4 waves (2x2),
// each wave 64x64 via 4x4 grid of 16x16x32 bf16 MFMA.
// global_load_lds width=16 staging, XOR-swizzled 16B chunks.
// Tile->block mapping is XCD-grouped: hardware ids go round-robin to the 8
// XCDs, so lid = (id&7)*(nblocks/8) + (id>>3) gives each XCD a contiguous
// stripe of N-fastest tiles -> A-panels land in exactly one XCD L2.
enum { EPI_BF16 = 0, EPI_RES = 1, EPI_SILU = 2, EPI_F32 = 3 };

template <int EPI>
__global__ void __launch_bounds__(256)
gemm_bt(const unsigned short* __restrict__ A,
        const unsigned short* __restrict__ W,
        const float* __restrict__ bias,
        const unsigned short* __restrict__ Res,
        void* __restrict__ Out,
        int K, int N) {
  __shared__ unsigned short As[128 * 64];
  __shared__ unsigned short Bs[128 * 64];
  const int t = threadIdx.x;
  const int lane = t & 63;
  const int wave = t >> 6;
  const int wm = wave >> 1, wn = wave & 1;

  const int nb = gridDim.x;
  const int nblocks = nb * gridDim.y;
  const int id = blockIdx.y * nb + blockIdx.x;
  const int lid = ((nblocks & 7) == 0) ? ((id & 7) * (nblocks >> 3) + (id >> 3)) : id;
  const long bm = (long)(lid / nb) * 128;
  const long bn = (long)(lid % nb) * 128;

  // staging: thread t -> LDS bytes [t*16, t*16+16) (+ issue*4KB), i.e. tile
  // row = t>>3 (+32*i), slot-chunk = t&7. Source k-chunk XOR-swizzled by row.
  const int srow = t >> 3;
  const int schunk = ((t & 7) ^ (srow & 7)) << 3;  // element offset
  const unsigned short* Ag = A + (bm + srow) * (long)K + schunk;
  const unsigned short* Wg = W + (bn + srow) * (long)K + schunk;
  unsigned short* AsD = As + t * 8;
  unsigned short* BsD = Bs + t * 8;

  f32x4 acc[4][4] = {};
  const int arow0 = wm * 64 + (lane & 15);
  const int brow0 = wn * 64 + (lane & 15);

  for (int k0 = 0; k0 < K; k0 += 64) {
    __syncthreads();
#pragma unroll
    for (int i = 0; i < 4; i++) {
      async_cp16(Ag + (long)(i * 32) * K + k0, AsD + i * 2048);
      async_cp16(Wg + (long)(i * 32) * K + k0, BsD + i * 2048);
    }
    __syncthreads();
#pragma unroll
    for (int kk = 0; kk < 2; kk++) {
      // global k-chunk q = kk*4 + (lane>>4); stored at slot q ^ (row&7); row&7 == lane&7
      const int sc = ((kk * 4 + (lane >> 4)) ^ (lane & 7)) << 3;
      bf16x8 af[4], bfr[4];
#pragma unroll
      for (int mt = 0; mt < 4; mt++)
        af[mt] = *(const bf16x8*)&As[(arow0 + mt * 16) * 64 + sc];
#pragma unroll
      for (int nt = 0; nt < 4; nt++)
        bfr[nt] = *(const bf16x8*)&Bs[(brow0 + nt * 16) * 64 + sc];
#pragma unroll
      for (int mt = 0; mt < 4; mt++)
#pragma unroll
        for (int nt = 0; nt < 4; nt++)
          acc[mt][nt] = __builtin_amdgcn_mfma_f32_16x16x32_bf16(
              af[mt], bfr[nt], acc[mt][nt], 0, 0, 0);
    }
  }

  // C/D layout: col = lane&15, row = (lane>>4)*4 + r
  const long row0 = bm + wm * 64 + ((lane >> 4) << 2);
  const int col0 = (int)bn + wn * 64 + (lane & 15);
#pragma unroll
  for (int nt = 0; nt < 4; nt++) {
    const int col = col0 + nt * 16;
    const float bv = bias[col];
#pragma unroll
    for (int mt = 0; mt < 4; mt++) {
      const long rbase = row0 + mt * 16;
#pragma unroll
      for (int r = 0; r < 4; r++) {
        float v = acc[mt][nt][r] + bv;
        const long idx = (rbase + r) * (long)N + col;
        if (EPI == EPI_RES) v += bf2f(Res[idx]);
        if (EPI == EPI_SILU) v = v * (1.0f / (1.0f + __expf(-v)));
        if (EPI == EPI_F32)
          ((float*)Out)[idx] = v;
        else
          ((unsigned short*)Out)[idx] = f2bf(v);
      }
    }
  }
}

// ---------------------------------------------------------------- attention
// one wave per (b, head-half). lane = 16*h_sub + l; head = 4*hh + h_sub;
// each lane owns d = 4*l..4*l+3 (ushort4 loads). 16-lane shuffle reduction.
__global__ void __launch_bounds__(256) attn3(const unsigned short* __restrict__ QKV,
                                             unsigned short* __restrict__ AO) {
  int unit = blockIdx.x * 4 + (threadIdx.x >> 6);  // b*2 + hh
  int lane = threadIdx.x & 63;
  int b = unit >> 1;
  int h = ((unit & 1) << 2) + (lane >> 4);
  int l = lane & 15;
  const unsigned short* base = QKV + (long)(3 * b) * 1536 + h * 64 + 4 * l;
  float q[3][4], k[3][4], v[3][4];
#pragma unroll
  for (int s = 0; s < 3; s++) {
    ushort4 qv = *(const ushort4*)(base + s * 1536);
    ushort4 kv = *(const ushort4*)(base + s * 1536 + 512);
    ushort4 vv = *(const ushort4*)(base + s * 1536 + 1024);
    q[s][0] = bf2f(qv.x); q[s][1] = bf2f(qv.y); q[s][2] = bf2f(qv.z); q[s][3] = bf2f(qv.w);
    k[s][0] = bf2f(kv.x); k[s][1] = bf2f(kv.y); k[s][2] = bf2f(kv.z); k[s][3] = bf2f(kv.w);
    v[s][0] = bf2f(vv.x); v[s][1] = bf2f(vv.y); v[s][2] = bf2f(vv.z); v[s][3] = bf2f(vv.w);
  }
  float sc[3][3];
#pragma unroll
  for (int s = 0; s < 3; s++)
#pragma unroll
    for (int u = 0; u < 3; u++)
      sc[s][u] = q[s][0] * k[u][0] + q[s][1] * k[u][1] +
                 q[s][2] * k[u][2] + q[s][3] * k[u][3];
#pragma unroll
  for (int m = 1; m < 16; m <<= 1)
#pragma unroll
    for (int s = 0; s < 3; s++)
#pragma unroll
      for (int u = 0; u < 3; u++) sc[s][u] += __shfl_xor(sc[s][u], m, 64);

  unsigned short* ob = AO + (long)(3 * b) * 512 + h * 64 + 4 * l;
#pragma unroll
  for (int s = 0; s < 3; s++) {
    float a0 = sc[s][0] * 0.125f, a1 = sc[s][1] * 0.125f, a2 = sc[s][2] * 0.125f;
    float mx = fmaxf(a0, fmaxf(a1, a2));
    float e0 = __expf(a0 - mx), e1 = __expf(a1 - mx), e2 = __expf(a2 - mx);
    float inv = 1.0f / (e0 + e1 + e2);
    ushort4 o;
    o.x = f2bf((e0 * v[0][0] + e1 * v[1][0] + e2 * v[2][0]) * inv);
    o.y = f2bf((e0 * v[0][1] + e1 * v[1][1] + e2 * v[2][1]) * inv);
    o.z = f2bf((e0 * v[0][2] + e1 * v[1][2] + e2 * v[2][2]) * inv);
    o.w = f2bf((e0 * v[0][3] + e1 * v[1][3] + e2 * v[2][3]) * inv);
    *(ushort4*)(ob + s * 512) = o;
  }
}

// ---------------------------------------------------------------- gate
// one block per batch row: 3 dots over 1536, softmax, scale, write gated bf16
__global__ void __launch_bounds__(256) gate3(const unsigned short* __restrict__ AT,
                                             const float* __restrict__ WG,
                                             const float* __restrict__ BG,
                                             unsigned short* __restrict__ G) {
  int b = blockIdx.x, t = threadIdx.x;
  const unsigned short* row = AT + (long)b * 1536;
  float x[6], p0 = 0.f, p1 = 0.f, p2 = 0.f;
#pragma unroll
  for (int i = 0; i < 6; i++) {
    int e = i * 256 + t;
    float xv = bf2f(row[e]);
    x[i] = xv;
    p0 = fmaf(xv, WG[e], p0);
    p1 = fmaf(xv, WG[1536 + e], p1);
    p2 = fmaf(xv, WG[3072 + e], p2);
  }
#pragma unroll
  for (int m = 1; m < 64; m <<= 1) {
    p0 += __shfl_xor(p0, m, 64);
    p1 += __shfl_xor(p1, m, 64);
    p2 += __shfl_xor(p2, m, 64);
  }
  __shared__ float red[3][4];
  int lane = t & 63, wave = t >> 6;
  if (lane == 0) { red[0][wave] = p0; red[1][wave] = p1; red[2][wave] = p2; }
  __syncthreads();
  float g0 = red[0][0] + red[0][1] + red[0][2] + red[0][3] + BG[0];
  float g1 = red[1][0] + red[1][1] + red[1][2] + red[1][3] + BG[1];
  float g2 = red[2][0] + red[2][1] + red[2][2] + red[2][3] + BG[2];
  float mx = fmaxf(g0, fmaxf(g1, g2));
  g0 = __expf(g0 - mx); g1 = __expf(g1 - mx); g2 = __expf(g2 - mx);
  float inv = 1.0f / (g0 + g1 + g2);
  g0 *= inv; g1 *= inv; g2 *= inv;
  unsigned short* outp = G + (long)b * 1536;
#pragma unroll
  for (int i = 0; i < 6; i++) {
    float gs = (i < 2) ? g0 : ((i < 4) ? g1 : g2);  // stream = e>>9 = i>>1
    outp[i * 256 + t] = f2bf(x[i] * gs);
  }
}

// ---------------------------------------------------------------- layernorm
// one wave per row of 512 f32
__global__ void __launch_bounds__(256) lnorm(const float* __restrict__ F,
                                             const float* __restrict__ gamma,
                                             const float* __restrict__ beta,
                                             float* __restrict__ out) {
  int row = blockIdx.x * 4 + (threadIdx.x >> 6);
  int lane = threadIdx.x & 63;
  const float4* fr = (const float4*)(F + (long)row * 512);
  float4 a = fr[lane], c = fr[lane + 64];
  float s = a.x + a.y + a.z + a.w + c.x + c.y + c.z + c.w;
  float ss = a.x * a.x + a.y * a.y + a.z * a.z + a.w * a.w +
             c.x * c.x + c.y * c.y + c.z * c.z + c.w * c.w;
#pragma unroll
  for (int m = 1; m < 64; m <<= 1) {
    s += __shfl_xor(s, m, 64);
    ss += __shfl_xor(ss, m, 64);
  }
  float mean = s * (1.0f / 512.0f);
  float var = ss * (1.0f / 512.0f) - mean * mean;
  float rstd = rsqrtf(var + 1e-5f);
  const float4* g4 = (const float4*)gamma;
  const float4* b4 = (const float4*)beta;
  float4 g0 = g4[lane], g1 = g4[lane + 64], be0 = b4[lane], be1 = b4[lane + 64];
  float4 o0, o1;
  o0.x = (a.x - mean) * rstd * g0.x + be0.x;
  o0.y = (a.y - mean) * rstd * g0.y + be0.y;
  o0.z = (a.z - mean) * rstd * g0.z + be0.z;
  o0.w = (a.w - mean) * rstd * g0.w + be0.w;
  o1.x = (c.x - mean) * rstd * g1.x + be1.x;
  o1.y = (c.y - mean) * rstd * g1.y + be1.y;
  o1.z = (c.z - mean) * rstd * g1.z + be1.z;
  o1.w = (c.w - mean) * rstd * g1.w + be1.w;
  float4* orow = (float4*)(out + (long)row * 512);
  orow[lane] = o0;
  orow[lane + 64] = o1;
}

// ---------------------------------------------------------------- launch
extern "C" void kernel_launch(void* const* d_in, const int* in_sizes, int n_in,
                              void* d_out, int out_size, void* d_ws, size_t ws_size,
                              hipStream_t stream) {
  const float* kin    = (const float*)d_in[0];
  const float* colr   = (const float*)d_in[1];
  const float* spi    = (const float*)d_in[2];
  const float* w_in   = (const float*)d_in[3];
  const float* b_in   = (const float*)d_in[4];
  const float* w_out  = (const float*)d_in[5];
  const float* b_out  = (const float*)d_in[6];
  const float* w_gate = (const float*)d_in[7];
  const float* b_gate = (const float*)d_in[8];
  const float* w1     = (const float*)d_in[9];
  const float* b1     = (const float*)d_in[10];
  const float* w2     = (const float*)d_in[11];
  const float* b2     = (const float*)d_in[12];
  const float* gamma  = (const float*)d_in[13];
  const float* beta   = (const float*)d_in[14];
  float* out = (float*)d_out;

  // chunk size: peak scratch = 6,291,456 + 15360*Bc bytes; shrink to fit ws_size
  long Bc = 32768;
  while (Bc > 1024 && (size_t)(6291456 + 15360 * Bc) > ws_size) Bc >>= 1;
  const int nch = (int)(32768 / Bc);

  // weights (bf16), converted once
  char* ws = (char*)d_ws;
  unsigned short* Wic = (unsigned short*)(ws);              // w_in  1536x512
  unsigned short* Woc = (unsigned short*)(ws + 1572864);    // w_out 512x512
  unsigned short* W1c = (unsigned short*)(ws + 2097152);    // w1    1024x1536
  unsigned short* W2c = (unsigned short*)(ws + 5242880);    // w2    512x1024
  char* Sb   = ws + 6291456;                                // S_c   [3Bc,512] bf16
  char* QKVb = Sb + 3072 * Bc;                              // QKV_c [3Bc,1536] bf16
  char* AOb  = QKVb + 9216 * Bc;                            // AO_c  [3Bc,512] bf16

  cvtbf<<<768, 256, 0, stream>>>((const float4*)w_in, (ushort4*)Wic, 196608);
  cvtbf<<<256, 256, 0, stream>>>((const float4*)w_out, (ushort4*)Woc, 65536);
  cvtbf<<<1536, 256, 0, stream>>>((const float4*)w1, (ushort4*)W1c, 393216);
  cvtbf<<<512, 256, 0, stream>>>((const float4*)w2, (ushort4*)W2c, 131072);

  for (int c = 0; c < nch; c++) {
    const long boff = (long)c * Bc;
    unsigned short* S_c   = (unsigned short*)Sb;
    unsigned short* QKV_c = (unsigned short*)QKVb;
    unsigned short* AO_c  = (unsigned short*)AOb;
    unsigned short* AT_c  = QKV_c;                          // [3Bc,512], aliases QKV (dead)
    unsigned short* G_c   = (unsigned short*)(QKVb + 3072 * Bc);  // [Bc,1536], after AT
    unsigned short* H_c   = AO_c;                           // [Bc,1024], aliases AO (dead)
    float*          F_c   = (float*)QKVb;                   // [Bc,512] f32, aliases AT (dead)

    pack3<<<(int)(Bc / 2), 256, 0, stream>>>(
        (const float4*)(kin + boff * 512), (const float4*)(colr + boff * 512),
        (const float4*)(spi + boff * 512), (ushort4*)S_c);
    // qkv = S @ w_in^T + b_in           M=3Bc N=1536 K=512
    gemm_bt<EPI_BF16><<<dim3(12, (int)(3 * Bc / 128)), 256, 0, stream>>>(
        S_c, Wic, b_in, nullptr, QKV_c, 512, 1536);
    attn3<<<(int)(Bc / 2), 256, 0, stream>>>(QKV_c, AO_c);
    // attn_out = S + AO @ w_out^T + b_out   M=3Bc N=512 K=512
    gemm_bt<EPI_RES><<<dim3(4, (int)(3 * Bc / 128)), 256, 0, stream>>>(
        AO_c, Woc, b_out, S_c, AT_c, 512, 512);
    gate3<<<(int)Bc, 256, 0, stream>>>(AT_c, w_gate, b_gate, G_c);
    // h = silu(G @ w1^T + b1)           M=Bc N=1024 K=1536
    gemm_bt<EPI_SILU><<<dim3(8, (int)(Bc / 128)), 256, 0, stream>>>(
        G_c, W1c, b1, nullptr, H_c, 1536, 1024);
    // fused = h @ w2^T + b2 (f32)       M=Bc N=512 K=1024
    gemm_bt<EPI_F32><<<dim3(4, (int)(Bc / 128)), 256, 0, stream>>>(
        H_c, W2c, b2, nullptr, F_c, 1024, 512);
    lnorm<<<(int)(Bc / 4), 256, 0, stream>>>(F_c, gamma, beta, out + boff * 512);
  }
}

// Round 4
// 823.155 us; speedup vs baseline: 1.3007x; 1.0518x over previous
//
#include <hip/hip_runtime.h>
#include <stdint.h>

// CrossStreamAttention: B=32768, D=512, H=8, S=3, DH=64
// R4: QKV-gemm + attention FUSED (QKV never materialized in HBM),
// vectorized gate, chunked pipeline (adaptive Bc).

typedef float f32x4 __attribute__((ext_vector_type(4)));
typedef short bf16x8 __attribute__((ext_vector_type(8)));  // 8 bf16 in 4 VGPRs

__device__ __forceinline__ float bf2f(unsigned short h) {
  return __uint_as_float(((unsigned)h) << 16);
}
__device__ __forceinline__ unsigned short f2bf(float f) {
  unsigned u = __float_as_uint(f);
  u += 0x7FFFu + ((u >> 16) & 1u);   // RNE
  return (unsigned short)(u >> 16);
}
__device__ __forceinline__ ushort4 f2bf4(float4 v) {
  return make_ushort4(f2bf(v.x), f2bf(v.y), f2bf(v.z), f2bf(v.w));
}

__device__ __forceinline__ void async_cp16(const void* g, void* lds) {
  __builtin_amdgcn_global_load_lds(
      (const __attribute__((address_space(1))) void*)g,
      (__attribute__((address_space(3))) void*)lds, 16, 0, 0);
}

// ---------------------------------------------------------------- converts
__global__ void __launch_bounds__(256) cvtbf(const float4* __restrict__ src,
                                             ushort4* __restrict__ dst, int n4) {
  int i = blockIdx.x * 256 + threadIdx.x;
  if (i < n4) dst[i] = f2bf4(src[i]);
}

// pack stacked[b,s,:] = input_s[b,:], bf16.  tid over Bc*128 float4s.
__global__ void __launch_bounds__(256) pack3(const float4* __restrict__ X0,
                                             const float4* __restrict__ X1,
                                             const float4* __restrict__ X2,
                                             ushort4* __restrict__ S) {
  int tid = blockIdx.x * 256 + threadIdx.x;   // b*128 + c
  int b = tid >> 7, c = tid & 127;
  long base = (long)(3 * b) * 128 + c;
  S[base]       = f2bf4(X0[tid]);
  S[base + 128] = f2bf4(X1[tid]);
  S[base + 256] = f2bf4(X2[tid]);
}

// ---------------------------------------------------------------- fused QKV gemm + attention
// grid (8 heads, 3Bc/96). Block: 96 rows (32 b's) x 192 cols (q|k|v strips of
// head h). K-loop: A 96x64 + B 192x64 async-staged, 4 waves in 2x2, each
// 48x96 via 3x6 MFMA 16x16x32. Then C(+bias)->bf16 into LDS (stride 200),
// attention per b in-LDS, AO written bf16. QKV never hits HBM.
__global__ void __launch_bounds__(256)
qkv_attn(const unsigned short* __restrict__ S,   // [3Bc,512]
         const unsigned short* __restrict__ Wi,  // [1536,512]
         const float* __restrict__ bin,          // [1536]
         unsigned short* __restrict__ AO) {      // [3Bc,512]
  __shared__ unsigned short lds[96 * 200];       // 38400 B; union staging/C
  unsigned short* Abuf = lds;                    // [96][64] during K-loop
  unsigned short* Bbuf = lds + 6144;             // [192][64] during K-loop

  const int t = threadIdx.x;
  const int lane = t & 63;
  const int wave = t >> 6;
  const int wm = wave >> 1, wn = wave & 1;
  const int h = blockIdx.x;
  const long m0 = (long)blockIdx.y * 96;

  // staging geometry: chunk c = r*256+t -> row=c>>3, kchunk slot = (t&7)^(row&7)
  const int trow = t >> 3;                       // 0..31 within a 32-row round
  const int swz = ((t & 7) ^ (trow & 7)) << 3;   // element offset (row&7==trow&7)
  const unsigned short* Ag = S + (m0 + trow) * 512 + swz;            // + r*32*512
  const unsigned short* Bg = Wi + ((long)h * 64 + trow) * 512 + swz; // + ((r>>1)*512+(r&1)*32)*512
  unsigned short* AsD = Abuf + t * 8;
  unsigned short* BsD = Bbuf + t * 8;

  f32x4 acc[3][6] = {};
  const int arow0 = wm * 48 + (lane & 15);
  const int brow0 = wn * 96 + (lane & 15);

  for (int k0 = 0; k0 < 512; k0 += 64) {
    __syncthreads();
#pragma unroll
    for (int r = 0; r < 3; r++)
      async_cp16(Ag + (long)r * 32 * 512 + k0, AsD + r * 2048);
#pragma unroll
    for (int r = 0; r < 6; r++)
      async_cp16(Bg + (long)((r >> 1) * 512 + (r & 1) * 32) * 512 + k0, BsD + r * 2048);
    __syncthreads();
#pragma unroll
    for (int kk = 0; kk < 2; kk++) {
      const int sc = ((kk * 4 + (lane >> 4)) ^ (lane & 7)) << 3;
      bf16x8 af[3], bfr[6];
#pragma unroll
      for (int mt = 0; mt < 3; mt++)
        af[mt] = *(const bf16x8*)&Abuf[(arow0 + mt * 16) * 64 + sc];
#pragma unroll
      for (int nt = 0; nt < 6; nt++)
        bfr[nt] = *(const bf16x8*)&Bbuf[(brow0 + nt * 16) * 64 + sc];
#pragma unroll
      for (int mt = 0; mt < 3; mt++)
#pragma unroll
        for (int nt = 0; nt < 6; nt++)
          acc[mt][nt] = __builtin_amdgcn_mfma_f32_16x16x32_bf16(
              af[mt], bfr[nt], acc[mt][nt], 0, 0, 0);
    }
  }

  // dump C (+bias) as bf16 into LDS, stride 200 (2-way max -> free)
  __syncthreads();
  const int crow0 = wm * 48 + ((lane >> 4) << 2);
  const int ccol0 = wn * 96 + (lane & 15);
#pragma unroll
  for (int nt = 0; nt < 6; nt++) {
    const int col = ccol0 + nt * 16;                 // 0..191
    const float bv = bin[(col >> 6) * 512 + h * 64 + (col & 63)];
#pragma unroll
    for (int mt = 0; mt < 3; mt++)
#pragma unroll
      for (int r = 0; r < 4; r++)
        lds[(crow0 + mt * 16 + r) * 200 + col] = f2bf(acc[mt][nt][r] + bv);
  }
  __syncthreads();

  // attention: wave handles 8 b's; lane = bi*8 + l8; lane owns d = l8*8..+7
  const int bi = lane >> 3;                          // 0..7 (b within wave's 8)
  const int l8 = lane & 7;
  const int r0 = (wave * 8 + bi) * 3;                // local row of stream 0
  float q[3][8], k[3][8], v[3][8];
#pragma unroll
  for (int s = 0; s < 3; s++) {
    const unsigned short* rowp = &lds[(r0 + s) * 200 + l8 * 8];
    uint4 qu = *(const uint4*)(rowp);
    uint4 ku = *(const uint4*)(rowp + 64);
    uint4 vu = *(const uint4*)(rowp + 128);
    const unsigned* qw = (const unsigned*)&qu;
    const unsigned* kw = (const unsigned*)&ku;
    const unsigned* vw = (const unsigned*)&vu;
#pragma unroll
    for (int j = 0; j < 4; j++) {
      q[s][2 * j]     = __uint_as_float(qw[j] << 16);
      q[s][2 * j + 1] = __uint_as_float(qw[j] & 0xffff0000u);
      k[s][2 * j]     = __uint_as_float(kw[j] << 16);
      k[s][2 * j + 1] = __uint_as_float(kw[j] & 0xffff0000u);
      v[s][2 * j]     = __uint_as_float(vw[j] << 16);
      v[s][2 * j + 1] = __uint_as_float(vw[j] & 0xffff0000u);
    }
  }
  float p[3][3];
#pragma unroll
  for (int s = 0; s < 3; s++)
#pragma unroll
    for (int u = 0; u < 3; u++) {
      float d = 0.f;
#pragma unroll
      for (int e = 0; e < 8; e++) d = fmaf(q[s][e], k[u][e], d);
      p[s][u] = d;
    }
  // reduce over the 8 lanes of this b (xor 1,2,4)
#pragma unroll
  for (int m = 1; m < 8; m <<= 1)
#pragma unroll
    for (int s = 0; s < 3; s++)
#pragma unroll
      for (int u = 0; u < 3; u++) p[s][u] += __shfl_xor(p[s][u], m, 64);

  unsigned short* ob = AO + (m0 + r0) * 512 + h * 64 + l8 * 8;
#pragma unroll
  for (int s = 0; s < 3; s++) {
    float a0 = p[s][0] * 0.125f, a1 = p[s][1] * 0.125f, a2 = p[s][2] * 0.125f;
    float mx = fmaxf(a0, fmaxf(a1, a2));
    float e0 = __expf(a0 - mx), e1 = __expf(a1 - mx), e2 = __expf(a2 - mx);
    float inv = 1.0f / (e0 + e1 + e2);
    unsigned ow[4];
#pragma unroll
    for (int j = 0; j < 4; j++) {
      float lo = (e0 * v[0][2 * j] + e1 * v[1][2 * j] + e2 * v[2][2 * j]) * inv;
      float hi = (e0 * v[0][2 * j + 1] + e1 * v[1][2 * j + 1] + e2 * v[2][2 * j + 1]) * inv;
      ow[j] = (unsigned)f2bf(lo) | ((unsigned)f2bf(hi) << 16);
    }
    *(uint4*)(ob + s * 512) = *(uint4*)ow;
  }
}

// ---------------------------------------------------------------- GEMM
// C[M,N] = A[M,K] @ W[N,K]^T + bias. 128x128 tile, BK=64, 4 waves (2x2),
// each wave 64x64 via 4x4 grid of 16x16x32 bf16 MFMA. XCD-grouped swizzle.
enum { EPI_BF16 = 0, EPI_RES = 1, EPI_SILU = 2, EPI_F32 = 3 };

template <int EPI>
__global__ void __launch_bounds__(256)
gemm_bt(const unsigned short* __restrict__ A,
        const unsigned short* __restrict__ W,
        const float* __restrict__ bias,
        const unsigned short* __restrict__ Res,
        void* __restrict__ Out,
        int K, int N) {
  __shared__ unsigned short As[128 * 64];
  __shared__ unsigned short Bs[128 * 64];
  const int t = threadIdx.x;
  const int lane = t & 63;
  const int wave = t >> 6;
  const int wm = wave >> 1, wn = wave & 1;

  const int nb = gridDim.x;
  const int nblocks = nb * gridDim.y;
  const int id = blockIdx.y * nb + blockIdx.x;
  const int lid = ((nblocks & 7) == 0) ? ((id & 7) * (nblocks >> 3) + (id >> 3)) : id;
  const long bm = (long)(lid / nb) * 128;
  const long bn = (long)(lid % nb) * 128;

  const int srow = t >> 3;
  const int schunk = ((t & 7) ^ (srow & 7)) << 3;  // element offset
  const unsigned short* Ag = A + (bm + srow) * (long)K + schunk;
  const unsigned short* Wg = W + (bn + srow) * (long)K + schunk;
  unsigned short* AsD = As + t * 8;
  unsigned short* BsD = Bs + t * 8;

  f32x4 acc[4][4] = {};
  const int arow0 = wm * 64 + (lane & 15);
  const int brow0 = wn * 64 + (lane & 15);

  for (int k0 = 0; k0 < K; k0 += 64) {
    __syncthreads();
#pragma unroll
    for (int i = 0; i < 4; i++) {
      async_cp16(Ag + (long)(i * 32) * K + k0, AsD + i * 2048);
      async_cp16(Wg + (long)(i * 32) * K + k0, BsD + i * 2048);
    }
    __syncthreads();
#pragma unroll
    for (int kk = 0; kk < 2; kk++) {
      const int sc = ((kk * 4 + (lane >> 4)) ^ (lane & 7)) << 3;
      bf16x8 af[4], bfr[4];
#pragma unroll
      for (int mt = 0; mt < 4; mt++)
        af[mt] = *(const bf16x8*)&As[(arow0 + mt * 16) * 64 + sc];
#pragma unroll
      for (int nt = 0; nt < 4; nt++)
        bfr[nt] = *(const bf16x8*)&Bs[(brow0 + nt * 16) * 64 + sc];
#pragma unroll
      for (int mt = 0; mt < 4; mt++)
#pragma unroll
        for (int nt = 0; nt < 4; nt++)
          acc[mt][nt] = __builtin_amdgcn_mfma_f32_16x16x32_bf16(
              af[mt], bfr[nt], acc[mt][nt], 0, 0, 0);
    }
  }

  // C/D layout: col = lane&15, row = (lane>>4)*4 + r
  const long row0 = bm + wm * 64 + ((lane >> 4) << 2);
  const int col0 = (int)bn + wn * 64 + (lane & 15);
#pragma unroll
  for (int nt = 0; nt < 4; nt++) {
    const int col = col0 + nt * 16;
    const float bv = bias[col];
#pragma unroll
    for (int mt = 0; mt < 4; mt++) {
      const long rbase = row0 + mt * 16;
#pragma unroll
      for (int r = 0; r < 4; r++) {
        float v = acc[mt][nt][r] + bv;
        const long idx = (rbase + r) * (long)N + col;
        if (EPI == EPI_RES) v += bf2f(Res[idx]);
        if (EPI == EPI_SILU) v = v * (1.0f / (1.0f + __expf(-v)));
        if (EPI == EPI_F32)
          ((float*)Out)[idx] = v;
        else
          ((unsigned short*)Out)[idx] = f2bf(v);
      }
    }
  }
}

// ---------------------------------------------------------------- gate
// one wave per batch row: 3 dots over 1536 with ushort8 loads, softmax,
// scale, vectorized write.
__global__ void __launch_bounds__(256) gate3(const unsigned short* __restrict__ AT,
                                             const float* __restrict__ WG,
                                             const float* __restrict__ BG,
                                             unsigned short* __restrict__ G) {
  int row = blockIdx.x * 4 + (threadIdx.x >> 6);
  int lane = threadIdx.x & 63;
  const unsigned short* rp = AT + (long)row * 1536 + lane * 8;
  float x[3][8];
  float p[3] = {0.f, 0.f, 0.f};
#pragma unroll
  for (int seg = 0; seg < 3; seg++) {
    uint4 u = *(const uint4*)(rp + seg * 512);
    const unsigned* uw = (const unsigned*)&u;
#pragma unroll
    for (int j = 0; j < 4; j++) {
      x[seg][2 * j]     = __uint_as_float(uw[j] << 16);
      x[seg][2 * j + 1] = __uint_as_float(uw[j] & 0xffff0000u);
    }
    const int e0 = seg * 512 + lane * 8;
#pragma unroll
    for (int g = 0; g < 3; g++) {
      const float* wp = WG + g * 1536 + e0;
#pragma unroll
      for (int e = 0; e < 8; e++) p[g] = fmaf(x[seg][e], wp[e], p[g]);
    }
  }
#pragma unroll
  for (int m = 1; m < 64; m <<= 1)
#pragma unroll
    for (int g = 0; g < 3; g++) p[g] += __shfl_xor(p[g], m, 64);
  float g0 = p[0] + BG[0], g1 = p[1] + BG[1], g2 = p[2] + BG[2];
  float mx = fmaxf(g0, fmaxf(g1, g2));
  g0 = __expf(g0 - mx); g1 = __expf(g1 - mx); g2 = __expf(g2 - mx);
  float inv = 1.0f / (g0 + g1 + g2);
  float gs[3] = {g0 * inv, g1 * inv, g2 * inv};
  unsigned short* op = G + (long)row * 1536 + lane * 8;
#pragma unroll
  for (int seg = 0; seg < 3; seg++) {
    unsigned ow[4];
#pragma unroll
    for (int j = 0; j < 4; j++)
      ow[j] = (unsigned)f2bf(x[seg][2 * j] * gs[seg]) |
              ((unsigned)f2bf(x[seg][2 * j + 1] * gs[seg]) << 16);
    *(uint4*)(op + seg * 512) = *(uint4*)ow;
  }
}

// ---------------------------------------------------------------- layernorm
// one wave per row of 512 f32
__global__ void __launch_bounds__(256) lnorm(const float* __restrict__ F,
                                             const float* __restrict__ gamma,
                                             const float* __restrict__ beta,
                                             float* __restrict__ out) {
  int row = blockIdx.x * 4 + (threadIdx.x >> 6);
  int lane = threadIdx.x & 63;
  const float4* fr = (const float4*)(F + (long)row * 512);
  float4 a = fr[lane], c = fr[lane + 64];
  float s = a.x + a.y + a.z + a.w + c.x + c.y + c.z + c.w;
  float ss = a.x * a.x + a.y * a.y + a.z * a.z + a.w * a.w +
             c.x * c.x + c.y * c.y + c.z * c.z + c.w * c.w;
#pragma unroll
  for (int m = 1; m < 64; m <<= 1) {
    s += __shfl_xor(s, m, 64);
    ss += __shfl_xor(ss, m, 64);
  }
  float mean = s * (1.0f / 512.0f);
  float var = ss * (1.0f / 512.0f) - mean * mean;
  float rstd = rsqrtf(var + 1e-5f);
  const float4* g4 = (const float4*)gamma;
  const float4* b4 = (const float4*)beta;
  float4 g0 = g4[lane], g1 = g4[lane + 64], be0 = b4[lane], be1 = b4[lane + 64];
  float4 o0, o1;
  o0.x = (a.x - mean) * rstd * g0.x + be0.x;
  o0.y = (a.y - mean) * rstd * g0.y + be0.y;
  o0.z = (a.z - mean) * rstd * g0.z + be0.z;
  o0.w = (a.w - mean) * rstd * g0.w + be0.w;
  o1.x = (c.x - mean) * rstd * g1.x + be1.x;
  o1.y = (c.y - mean) * rstd * g1.y + be1.y;
  o1.z = (c.z - mean) * rstd * g1.z + be1.z;
  o1.w = (c.w - mean) * rstd * g1.w + be1.w;
  float4* orow = (float4*)(out + (long)row * 512);
  orow[lane] = o0;
  orow[lane + 64] = o1;
}

// ---------------------------------------------------------------- launch
extern "C" void kernel_launch(void* const* d_in, const int* in_sizes, int n_in,
                              void* d_out, int out_size, void* d_ws, size_t ws_size,
                              hipStream_t stream) {
  const float* kin    = (const float*)d_in[0];
  const float* colr   = (const float*)d_in[1];
  const float* spi    = (const float*)d_in[2];
  const float* w_in   = (const float*)d_in[3];
  const float* b_in   = (const float*)d_in[4];
  const float* w_out  = (const float*)d_in[5];
  const float* b_out  = (const float*)d_in[6];
  const float* w_gate = (const float*)d_in[7];
  const float* b_gate = (const float*)d_in[8];
  const float* w1     = (const float*)d_in[9];
  const float* b1     = (const float*)d_in[10];
  const float* w2     = (const float*)d_in[11];
  const float* b2     = (const float*)d_in[12];
  const float* gamma  = (const float*)d_in[13];
  const float* beta   = (const float*)d_in[14];
  float* out = (float*)d_out;

  // scratch: weights 6,291,456 + S/AO/AT/G buffers = 12288*Bc
  long Bc = 32768;
  while (Bc > 1024 && (size_t)(6291456 + 12288 * Bc) > ws_size) Bc >>= 1;
  const int nch = (int)(32768 / Bc);

  char* ws = (char*)d_ws;
  unsigned short* Wic = (unsigned short*)(ws);              // w_in  1536x512
  unsigned short* Woc = (unsigned short*)(ws + 1572864);    // w_out 512x512
  unsigned short* W1c = (unsigned short*)(ws + 2097152);    // w1    1024x1536
  unsigned short* W2c = (unsigned short*)(ws + 5242880);    // w2    512x1024
  char* Sb  = ws + 6291456;                                 // S  [3Bc,512] bf16
  char* AOb = Sb + 3072 * Bc;                               // AO [3Bc,512] bf16
  char* ATb = AOb + 3072 * Bc;                              // AT [3Bc,512] bf16
  char* Gb  = ATb + 3072 * Bc;                              // G  [Bc,1536] bf16

  cvtbf<<<768, 256, 0, stream>>>((const float4*)w_in, (ushort4*)Wic, 196608);
  cvtbf<<<256, 256, 0, stream>>>((const float4*)w_out, (ushort4*)Woc, 65536);
  cvtbf<<<1536, 256, 0, stream>>>((const float4*)w1, (ushort4*)W1c, 393216);
  cvtbf<<<512, 256, 0, stream>>>((const float4*)w2, (ushort4*)W2c, 131072);

  for (int c = 0; c < nch; c++) {
    const long boff = (long)c * Bc;
    unsigned short* S_c  = (unsigned short*)Sb;
    unsigned short* AO_c = (unsigned short*)AOb;
    unsigned short* AT_c = (unsigned short*)ATb;
    unsigned short* G_c  = (unsigned short*)Gb;
    unsigned short* H_c  = (unsigned short*)AOb;   // [Bc,1024], AO dead after proj
    float*          F_c  = (float*)ATb;            // [Bc,512] f32, AT dead after gate

    pack3<<<(int)(Bc / 2), 256, 0, stream>>>(
        (const float4*)(kin + boff * 512), (const float4*)(colr + boff * 512),
        (const float4*)(spi + boff * 512), (ushort4*)S_c);
    // fused qkv-gemm + attention: S -> AO
    qkv_attn<<<dim3(8, (int)(Bc / 32)), 256, 0, stream>>>(S_c, Wic, b_in, AO_c);
    // attn_out = S + AO @ w_out^T + b_out   M=3Bc N=512 K=512
    gemm_bt<EPI_RES><<<dim3(4, (int)(3 * Bc / 128)), 256, 0, stream>>>(
        AO_c, Woc, b_out, S_c, AT_c, 512, 512);
    gate3<<<(int)(Bc / 4), 256, 0, stream>>>(AT_c, w_gate, b_gate, G_c);
    // h = silu(G @ w1^T + b1)           M=Bc N=1024 K=1536
    gemm_bt<EPI_SILU><<<dim3(8, (int)(Bc / 128)), 256, 0, stream>>>(
        G_c, W1c, b1, nullptr, H_c, 1536, 1024);
    // fused = h @ w2^T + b2 (f32)       M=Bc N=512 K=1024
    gemm_bt<EPI_F32><<<dim3(4, (int)(Bc / 128)), 256, 0, stream>>>(
        H_c, W2c, b2, nullptr, F_c, 1024, 512);
    lnorm<<<(int)(Bc / 4), 256, 0, stream>>>(F_c, gamma, beta, out + boff * 512);
  }
}

// Round 5
// 794.753 us; speedup vs baseline: 1.3472x; 1.0357x over previous
//
#include <hip/hip_runtime.h>
#include <stdint.h>

// CrossStreamAttention: B=32768, D=512, H=8, S=3, DH=64
// R5: qkv_attn XCD-grouped tile remap (8 head-blocks of one A-panel share an
// XCD L2), in-place gate (G==AT) -> scratch 9216*Bc+6.3MB -> Bc=32768 single
// chunk when ws allows.

typedef float f32x4 __attribute__((ext_vector_type(4)));
typedef short bf16x8 __attribute__((ext_vector_type(8)));  // 8 bf16 in 4 VGPRs

__device__ __forceinline__ float bf2f(unsigned short h) {
  return __uint_as_float(((unsigned)h) << 16);
}
__device__ __forceinline__ unsigned short f2bf(float f) {
  unsigned u = __float_as_uint(f);
  u += 0x7FFFu + ((u >> 16) & 1u);   // RNE
  return (unsigned short)(u >> 16);
}
__device__ __forceinline__ ushort4 f2bf4(float4 v) {
  return make_ushort4(f2bf(v.x), f2bf(v.y), f2bf(v.z), f2bf(v.w));
}

__device__ __forceinline__ void async_cp16(const void* g, void* lds) {
  __builtin_amdgcn_global_load_lds(
      (const __attribute__((address_space(1))) void*)g,
      (__attribute__((address_space(3))) void*)lds, 16, 0, 0);
}

// ---------------------------------------------------------------- converts
__global__ void __launch_bounds__(256) cvtbf(const float4* __restrict__ src,
                                             ushort4* __restrict__ dst, int n4) {
  int i = blockIdx.x * 256 + threadIdx.x;
  if (i < n4) dst[i] = f2bf4(src[i]);
}

// pack stacked[b,s,:] = input_s[b,:], bf16.  tid over Bc*128 float4s.
__global__ void __launch_bounds__(256) pack3(const float4* __restrict__ X0,
                                             const float4* __restrict__ X1,
                                             const float4* __restrict__ X2,
                                             ushort4* __restrict__ S) {
  int tid = blockIdx.x * 256 + threadIdx.x;   // b*128 + c
  int b = tid >> 7, c = tid & 127;
  long base = (long)(3 * b) * 128 + c;
  S[base]       = f2bf4(X0[tid]);
  S[base + 128] = f2bf4(X1[tid]);
  S[base + 256] = f2bf4(X2[tid]);
}

// ---------------------------------------------------------------- fused QKV gemm + attention
// grid (8, ny). Logical tile: 96 rows (32 b's) x 192 cols (q|k|v of head h).
// XCD-grouped remap: hw id = y*8+x; xcd = id&7; j = id>>3; h = j&7;
// panel = xcd*(ny/8) + (j>>3)  ->  8 consecutive blocks on one XCD share one
// A-panel (L2-local). Requires ny % 8 == 0 (ny = Bc/32, Bc % 256 == 0).
// K-loop: A 96x64 + B 192x64 async-staged, 4 waves 2x2, each 48x96 = 3x6
// MFMA 16x16x32. Then C(+bias)->bf16 in LDS (stride 200), per-b attention
// in-LDS, AO written bf16. QKV never hits HBM.
__global__ void __launch_bounds__(256)
qkv_attn(const unsigned short* __restrict__ S,   // [3Bc,512]
         const unsigned short* __restrict__ Wi,  // [1536,512]
         const float* __restrict__ bin,          // [1536]
         unsigned short* __restrict__ AO) {      // [3Bc,512]
  __shared__ unsigned short lds[96 * 200];       // 38400 B; union staging/C
  unsigned short* Abuf = lds;                    // [96][64] during K-loop
  unsigned short* Bbuf = lds + 6144;             // [192][64] during K-loop

  const int t = threadIdx.x;
  const int lane = t & 63;
  const int wave = t >> 6;
  const int wm = wave >> 1, wn = wave & 1;

  const int ny = gridDim.y;
  const int id = blockIdx.y * 8 + blockIdx.x;
  const int xcd = id & 7, j = id >> 3;
  const int h = j & 7;
  const long m0 = (long)(xcd * (ny >> 3) + (j >> 3)) * 96;

  // staging geometry: chunk c = r*256+t -> row=c>>3, kchunk slot = (t&7)^(row&7)
  const int trow = t >> 3;                       // 0..31 within a 32-row round
  const int swz = ((t & 7) ^ (trow & 7)) << 3;   // element offset (row&7==trow&7)
  const unsigned short* Ag = S + (m0 + trow) * 512 + swz;            // + r*32*512
  const unsigned short* Bg = Wi + ((long)h * 64 + trow) * 512 + swz; // + ((r>>1)*512+(r&1)*32)*512
  unsigned short* AsD = Abuf + t * 8;
  unsigned short* BsD = Bbuf + t * 8;

  f32x4 acc[3][6] = {};
  const int arow0 = wm * 48 + (lane & 15);
  const int brow0 = wn * 96 + (lane & 15);

  for (int k0 = 0; k0 < 512; k0 += 64) {
    __syncthreads();
#pragma unroll
    for (int r = 0; r < 3; r++)
      async_cp16(Ag + (long)r * 32 * 512 + k0, AsD + r * 2048);
#pragma unroll
    for (int r = 0; r < 6; r++)
      async_cp16(Bg + (long)((r >> 1) * 512 + (r & 1) * 32) * 512 + k0, BsD + r * 2048);
    __syncthreads();
#pragma unroll
    for (int kk = 0; kk < 2; kk++) {
      const int sc = ((kk * 4 + (lane >> 4)) ^ (lane & 7)) << 3;
      bf16x8 af[3], bfr[6];
#pragma unroll
      for (int mt = 0; mt < 3; mt++)
        af[mt] = *(const bf16x8*)&Abuf[(arow0 + mt * 16) * 64 + sc];
#pragma unroll
      for (int nt = 0; nt < 6; nt++)
        bfr[nt] = *(const bf16x8*)&Bbuf[(brow0 + nt * 16) * 64 + sc];
#pragma unroll
      for (int mt = 0; mt < 3; mt++)
#pragma unroll
        for (int nt = 0; nt < 6; nt++)
          acc[mt][nt] = __builtin_amdgcn_mfma_f32_16x16x32_bf16(
              af[mt], bfr[nt], acc[mt][nt], 0, 0, 0);
    }
  }

  // dump C (+bias) as bf16 into LDS, stride 200
  __syncthreads();
  const int crow0 = wm * 48 + ((lane >> 4) << 2);
  const int ccol0 = wn * 96 + (lane & 15);
#pragma unroll
  for (int nt = 0; nt < 6; nt++) {
    const int col = ccol0 + nt * 16;                 // 0..191
    const float bv = bin[(col >> 6) * 512 + h * 64 + (col & 63)];
#pragma unroll
    for (int mt = 0; mt < 3; mt++)
#pragma unroll
      for (int r = 0; r < 4; r++)
        lds[(crow0 + mt * 16 + r) * 200 + col] = f2bf(acc[mt][nt][r] + bv);
  }
  __syncthreads();

  // attention: wave handles 8 b's; lane = bi*8 + l8; lane owns d = l8*8..+7
  const int bi = lane >> 3;                          // 0..7 (b within wave's 8)
  const int l8 = lane & 7;
  const int r0 = (wave * 8 + bi) * 3;                // local row of stream 0
  float q[3][8], k[3][8], v[3][8];
#pragma unroll
  for (int s = 0; s < 3; s++) {
    const unsigned short* rowp = &lds[(r0 + s) * 200 + l8 * 8];
    uint4 qu = *(const uint4*)(rowp);
    uint4 ku = *(const uint4*)(rowp + 64);
    uint4 vu = *(const uint4*)(rowp + 128);
    const unsigned* qw = (const unsigned*)&qu;
    const unsigned* kw = (const unsigned*)&ku;
    const unsigned* vw = (const unsigned*)&vu;
#pragma unroll
    for (int jj = 0; jj < 4; jj++) {
      q[s][2 * jj]     = __uint_as_float(qw[jj] << 16);
      q[s][2 * jj + 1] = __uint_as_float(qw[jj] & 0xffff0000u);
      k[s][2 * jj]     = __uint_as_float(kw[jj] << 16);
      k[s][2 * jj + 1] = __uint_as_float(kw[jj] & 0xffff0000u);
      v[s][2 * jj]     = __uint_as_float(vw[jj] << 16);
      v[s][2 * jj + 1] = __uint_as_float(vw[jj] & 0xffff0000u);
    }
  }
  float p[3][3];
#pragma unroll
  for (int s = 0; s < 3; s++)
#pragma unroll
    for (int u = 0; u < 3; u++) {
      float d = 0.f;
#pragma unroll
      for (int e = 0; e < 8; e++) d = fmaf(q[s][e], k[u][e], d);
      p[s][u] = d;
    }
#pragma unroll
  for (int m = 1; m < 8; m <<= 1)
#pragma unroll
    for (int s = 0; s < 3; s++)
#pragma unroll
      for (int u = 0; u < 3; u++) p[s][u] += __shfl_xor(p[s][u], m, 64);

  unsigned short* ob = AO + (m0 + r0) * 512 + h * 64 + l8 * 8;
#pragma unroll
  for (int s = 0; s < 3; s++) {
    float a0 = p[s][0] * 0.125f, a1 = p[s][1] * 0.125f, a2 = p[s][2] * 0.125f;
    float mx = fmaxf(a0, fmaxf(a1, a2));
    float e0 = __expf(a0 - mx), e1 = __expf(a1 - mx), e2 = __expf(a2 - mx);
    float inv = 1.0f / (e0 + e1 + e2);
    unsigned ow[4];
#pragma unroll
    for (int jj = 0; jj < 4; jj++) {
      float lo = (e0 * v[0][2 * jj] + e1 * v[1][2 * jj] + e2 * v[2][2 * jj]) * inv;
      float hi = (e0 * v[0][2 * jj + 1] + e1 * v[1][2 * jj + 1] + e2 * v[2][2 * jj + 1]) * inv;
      ow[jj] = (unsigned)f2bf(lo) | ((unsigned)f2bf(hi) << 16);
    }
    *(uint4*)(ob + s * 512) = *(uint4*)ow;
  }
}

// ---------------------------------------------------------------- GEMM
// C[M,N] = A[M,K] @ W[N,K]^T + bias. 128x128 tile, BK=64, 4 waves (2x2),
// each wave 64x64 via 4x4 grid of 16x16x32 bf16 MFMA. XCD-grouped swizzle.
enum { EPI_BF16 = 0, EPI_RES = 1, EPI_SILU = 2, EPI_F32 = 3 };

template <int EPI>
__global__ void __launch_bounds__(256)
gemm_bt(const unsigned short* __restrict__ A,
        const unsigned short* __restrict__ W,
        const float* __restrict__ bias,
        const unsigned short* __restrict__ Res,
        void* __restrict__ Out,
        int K, int N) {
  __shared__ unsigned short As[128 * 64];
  __shared__ unsigned short Bs[128 * 64];
  const int t = threadIdx.x;
  const int lane = t & 63;
  const int wave = t >> 6;
  const int wm = wave >> 1, wn = wave & 1;

  const int nb = gridDim.x;
  const int nblocks = nb * gridDim.y;
  const int id = blockIdx.y * nb + blockIdx.x;
  const int lid = ((nblocks & 7) == 0) ? ((id & 7) * (nblocks >> 3) + (id >> 3)) : id;
  const long bm = (long)(lid / nb) * 128;
  const long bn = (long)(lid % nb) * 128;

  const int srow = t >> 3;
  const int schunk = ((t & 7) ^ (srow & 7)) << 3;  // element offset
  const unsigned short* Ag = A + (bm + srow) * (long)K + schunk;
  const unsigned short* Wg = W + (bn + srow) * (long)K + schunk;
  unsigned short* AsD = As + t * 8;
  unsigned short* BsD = Bs + t * 8;

  f32x4 acc[4][4] = {};
  const int arow0 = wm * 64 + (lane & 15);
  const int brow0 = wn * 64 + (lane & 15);

  for (int k0 = 0; k0 < K; k0 += 64) {
    __syncthreads();
#pragma unroll
    for (int i = 0; i < 4; i++) {
      async_cp16(Ag + (long)(i * 32) * K + k0, AsD + i * 2048);
      async_cp16(Wg + (long)(i * 32) * K + k0, BsD + i * 2048);
    }
    __syncthreads();
#pragma unroll
    for (int kk = 0; kk < 2; kk++) {
      const int sc = ((kk * 4 + (lane >> 4)) ^ (lane & 7)) << 3;
      bf16x8 af[4], bfr[4];
#pragma unroll
      for (int mt = 0; mt < 4; mt++)
        af[mt] = *(const bf16x8*)&As[(arow0 + mt * 16) * 64 + sc];
#pragma unroll
      for (int nt = 0; nt < 4; nt++)
        bfr[nt] = *(const bf16x8*)&Bs[(brow0 + nt * 16) * 64 + sc];
#pragma unroll
      for (int mt = 0; mt < 4; mt++)
#pragma unroll
        for (int nt = 0; nt < 4; nt++)
          acc[mt][nt] = __builtin_amdgcn_mfma_f32_16x16x32_bf16(
              af[mt], bfr[nt], acc[mt][nt], 0, 0, 0);
    }
  }

  // C/D layout: col = lane&15, row = (lane>>4)*4 + r
  const long row0 = bm + wm * 64 + ((lane >> 4) << 2);
  const int col0 = (int)bn + wn * 64 + (lane & 15);
#pragma unroll
  for (int nt = 0; nt < 4; nt++) {
    const int col = col0 + nt * 16;
    const float bv = bias[col];
#pragma unroll
    for (int mt = 0; mt < 4; mt++) {
      const long rbase = row0 + mt * 16;
#pragma unroll
      for (int r = 0; r < 4; r++) {
        float v = acc[mt][nt][r] + bv;
        const long idx = (rbase + r) * (long)N + col;
        if (EPI == EPI_RES) v += bf2f(Res[idx]);
        if (EPI == EPI_SILU) v = v * (1.0f / (1.0f + __expf(-v)));
        if (EPI == EPI_F32)
          ((float*)Out)[idx] = v;
        else
          ((unsigned short*)Out)[idx] = f2bf(v);
      }
    }
  }
}

// ---------------------------------------------------------------- gate
// one wave per batch row, ushort8 loads; in-place safe (each wave reads only
// the elements it writes, all reads precede all writes).
__global__ void __launch_bounds__(256) gate3(const unsigned short* AT,
                                             const float* __restrict__ WG,
                                             const float* __restrict__ BG,
                                             unsigned short* G) {
  int row = blockIdx.x * 4 + (threadIdx.x >> 6);
  int lane = threadIdx.x & 63;
  const unsigned short* rp = AT + (long)row * 1536 + lane * 8;
  float x[3][8];
  float p[3] = {0.f, 0.f, 0.f};
#pragma unroll
  for (int seg = 0; seg < 3; seg++) {
    uint4 u = *(const uint4*)(rp + seg * 512);
    const unsigned* uw = (const unsigned*)&u;
#pragma unroll
    for (int j = 0; j < 4; j++) {
      x[seg][2 * j]     = __uint_as_float(uw[j] << 16);
      x[seg][2 * j + 1] = __uint_as_float(uw[j] & 0xffff0000u);
    }
    const int e0 = seg * 512 + lane * 8;
#pragma unroll
    for (int g = 0; g < 3; g++) {
      const float* wp = WG + g * 1536 + e0;
#pragma unroll
      for (int e = 0; e < 8; e++) p[g] = fmaf(x[seg][e], wp[e], p[g]);
    }
  }
#pragma unroll
  for (int m = 1; m < 64; m <<= 1)
#pragma unroll
    for (int g = 0; g < 3; g++) p[g] += __shfl_xor(p[g], m, 64);
  float g0 = p[0] + BG[0], g1 = p[1] + BG[1], g2 = p[2] + BG[2];
  float mx = fmaxf(g0, fmaxf(g1, g2));
  g0 = __expf(g0 - mx); g1 = __expf(g1 - mx); g2 = __expf(g2 - mx);
  float inv = 1.0f / (g0 + g1 + g2);
  float gs[3] = {g0 * inv, g1 * inv, g2 * inv};
  unsigned short* op = G + (long)row * 1536 + lane * 8;
#pragma unroll
  for (int seg = 0; seg < 3; seg++) {
    unsigned ow[4];
#pragma unroll
    for (int j = 0; j < 4; j++)
      ow[j] = (unsigned)f2bf(x[seg][2 * j] * gs[seg]) |
              ((unsigned)f2bf(x[seg][2 * j + 1] * gs[seg]) << 16);
    *(uint4*)(op + seg * 512) = *(uint4*)ow;
  }
}

// ---------------------------------------------------------------- layernorm
// one wave per row of 512 f32
__global__ void __launch_bounds__(256) lnorm(const float* __restrict__ F,
                                             const float* __restrict__ gamma,
                                             const float* __restrict__ beta,
                                             float* __restrict__ out) {
  int row = blockIdx.x * 4 + (threadIdx.x >> 6);
  int lane = threadIdx.x & 63;
  const float4* fr = (const float4*)(F + (long)row * 512);
  float4 a = fr[lane], c = fr[lane + 64];
  float s = a.x + a.y + a.z + a.w + c.x + c.y + c.z + c.w;
  float ss = a.x * a.x + a.y * a.y + a.z * a.z + a.w * a.w +
             c.x * c.x + c.y * c.y + c.z * c.z + c.w * c.w;
#pragma unroll
  for (int m = 1; m < 64; m <<= 1) {
    s += __shfl_xor(s, m, 64);
    ss += __shfl_xor(ss, m, 64);
  }
  float mean = s * (1.0f / 512.0f);
  float var = ss * (1.0f / 512.0f) - mean * mean;
  float rstd = rsqrtf(var + 1e-5f);
  const float4* g4 = (const float4*)gamma;
  const float4* b4 = (const float4*)beta;
  float4 g0 = g4[lane], g1 = g4[lane + 64], be0 = b4[lane], be1 = b4[lane + 64];
  float4 o0, o1;
  o0.x = (a.x - mean) * rstd * g0.x + be0.x;
  o0.y = (a.y - mean) * rstd * g0.y + be0.y;
  o0.z = (a.z - mean) * rstd * g0.z + be0.z;
  o0.w = (a.w - mean) * rstd * g0.w + be0.w;
  o1.x = (c.x - mean) * rstd * g1.x + be1.x;
  o1.y = (c.y - mean) * rstd * g1.y + be1.y;
  o1.z = (c.z - mean) * rstd * g1.z + be1.z;
  o1.w = (c.w - mean) * rstd * g1.w + be1.w;
  float4* orow = (float4*)(out + (long)row * 512);
  orow[lane] = o0;
  orow[lane + 64] = o1;
}

// ---------------------------------------------------------------- launch
extern "C" void kernel_launch(void* const* d_in, const int* in_sizes, int n_in,
                              void* d_out, int out_size, void* d_ws, size_t ws_size,
                              hipStream_t stream) {
  const float* kin    = (const float*)d_in[0];
  const float* colr   = (const float*)d_in[1];
  const float* spi    = (const float*)d_in[2];
  const float* w_in   = (const float*)d_in[3];
  const float* b_in   = (const float*)d_in[4];
  const float* w_out  = (const float*)d_in[5];
  const float* b_out  = (const float*)d_in[6];
  const float* w_gate = (const float*)d_in[7];
  const float* b_gate = (const float*)d_in[8];
  const float* w1     = (const float*)d_in[9];
  const float* b1     = (const float*)d_in[10];
  const float* w2     = (const float*)d_in[11];
  const float* b2     = (const float*)d_in[12];
  const float* gamma  = (const float*)d_in[13];
  const float* beta   = (const float*)d_in[14];
  float* out = (float*)d_out;

  // scratch: weights 6,291,456 + S/AO/AT = 9216*Bc (gate in-place, F aliases S)
  long Bc = 32768;
  while (Bc > 1024 && (size_t)(6291456 + 9216 * Bc) > ws_size) Bc >>= 1;
  const int nch = (int)(32768 / Bc);

  char* ws = (char*)d_ws;
  unsigned short* Wic = (unsigned short*)(ws);              // w_in  1536x512
  unsigned short* Woc = (unsigned short*)(ws + 1572864);    // w_out 512x512
  unsigned short* W1c = (unsigned short*)(ws + 2097152);    // w1    1024x1536
  unsigned short* W2c = (unsigned short*)(ws + 5242880);    // w2    512x1024
  char* Sb  = ws + 6291456;                                 // S  [3Bc,512] bf16
  char* AOb = Sb + 3072 * Bc;                               // AO [3Bc,512] bf16
  char* ATb = AOb + 3072 * Bc;                              // AT [3Bc,512] bf16

  cvtbf<<<768, 256, 0, stream>>>((const float4*)w_in, (ushort4*)Wic, 196608);
  cvtbf<<<256, 256, 0, stream>>>((const float4*)w_out, (ushort4*)Woc, 65536);
  cvtbf<<<1536, 256, 0, stream>>>((const float4*)w1, (ushort4*)W1c, 393216);
  cvtbf<<<512, 256, 0, stream>>>((const float4*)w2, (ushort4*)W2c, 131072);

  for (int c = 0; c < nch; c++) {
    const long boff = (long)c * Bc;
    unsigned short* S_c  = (unsigned short*)Sb;
    unsigned short* AO_c = (unsigned short*)AOb;
    unsigned short* AT_c = (unsigned short*)ATb;
    unsigned short* G_c  = AT_c;                   // gate in-place
    unsigned short* H_c  = (unsigned short*)AOb;   // [Bc,1024], AO dead after proj
    float*          F_c  = (float*)Sb;             // [Bc,512] f32, S dead after proj

    pack3<<<(int)(Bc / 2), 256, 0, stream>>>(
        (const float4*)(kin + boff * 512), (const float4*)(colr + boff * 512),
        (const float4*)(spi + boff * 512), (ushort4*)S_c);
    // fused qkv-gemm + attention: S -> AO
    qkv_attn<<<dim3(8, (int)(Bc / 32)), 256, 0, stream>>>(S_c, Wic, b_in, AO_c);
    // attn_out = S + AO @ w_out^T + b_out   M=3Bc N=512 K=512
    gemm_bt<EPI_RES><<<dim3(4, (int)(3 * Bc / 128)), 256, 0, stream>>>(
        AO_c, Woc, b_out, S_c, AT_c, 512, 512);
    gate3<<<(int)(Bc / 4), 256, 0, stream>>>(AT_c, w_gate, b_gate, G_c);
    // h = silu(G @ w1^T + b1)           M=Bc N=1024 K=1536
    gemm_bt<EPI_SILU><<<dim3(8, (int)(Bc / 128)), 256, 0, stream>>>(
        G_c, W1c, b1, nullptr, H_c, 1536, 1024);
    // fused = h @ w2^T + b2 (f32)       M=Bc N=512 K=1024
    gemm_bt<EPI_F32><<<dim3(4, (int)(Bc / 128)), 256, 0, stream>>>(
        H_c, W2c, b2, nullptr, F_c, 1024, 512);
    lnorm<<<(int)(Bc / 4), 256, 0, stream>>>(F_c, gamma, beta, out + boff * 512);
  }
}